// Round 3
// baseline (150.504 us; speedup 1.0000x reference)
//
#include <hip/hip_runtime.h>

// Problem constants (B,R,C = 32, NB=2, NC=20)
#define Bdim 32
#define Rdim 32
#define Cdim 32
#define NBOX 2
#define NCLS 20
#define CH   174   // 6 + 2*(R+C) + 2*NC
#define CHP  348   // NB * CH
#define BASE 134   // 6 + 2*(R+C)
#define NCELL (Bdim * Rdim * Cdim)   // 32768

// Per-cell 4-bit records. Static device memory: zero-initialized at module
// load, and emit_kernel re-zeros each cell after consuming it, so the
// zero-invariant holds across timed iterations with NO memset launch and NO
// d_ws dependency (round-2 container failure suspect: unknown ws_size).
//   bit0 = flag(cell)          bit1 = best(cell)
//   bit2 = some flagged cell's corner == this cell with best=0
//   bit3 = same with best=1
__device__ unsigned g_mask[NCELL];

// ---------------------------------------------------------------------------
// Kernel A: per-cell match. One wave per cell; wave-uniform flag branch;
// ballot argmax of the one-hot row/col pointers; redundant per-lane score
// math (all loads wave-uniform broadcast). atomicOr is idempotent -> safe
// under rocprof counter-replay.
// ---------------------------------------------------------------------------
__global__ __launch_bounds__(256) void match_kernel(
    const float* __restrict__ pred, const float* __restrict__ label)
{
    const int wave = (blockIdx.x << 2) | (threadIdx.x >> 6);   // cell index
    const int lane = threadIdx.x & 63;
    const int c = wave & 31;
    const int r = (wave >> 5) & 31;
    const int b = wave >> 10;

    const float* Lcell = label + (size_t)wave * CH;

    // flag: exact == 1.0 test (wave-uniform)
    if (Lcell[0] != 1.0f) return;

    // argmax of one-hot via ballot (first set bit == first max index)
    float vr = (lane < 32) ? Lcell[6 + lane] : 0.0f;
    float vc = (lane < 32) ? Lcell[6 + 32 + lane] : 0.0f;
    unsigned long long mr = __ballot(lane < 32 && vr == 1.0f);
    unsigned long long mc = __ballot(lane < 32 && vc == 1.0f);
    const int rowc = mr ? (int)__builtin_ctzll(mr) : 0;
    const int colc = mc ? (int)__builtin_ctzll(mc) : 0;

    const int cornIdx = (b * Rdim + rowc) * Cdim + colc;
    const float* Lcorn = label + (size_t)cornIdx * CH;
    const float* Pcell = pred + (size_t)wave * CHP;
    const float* Pcorn = pred + (size_t)cornIdx * CHP;

    // ground-truth box (division by 32 == exact *0.03125)
    const float inv = 0.03125f;
    float xm_t = (Lcell[2] + (float)c) * inv;
    float ym_t = (Lcell[3] + (float)r) * inv;
    float xc_t = (Lcorn[4] + (float)colc) * inv;
    float yc_t = (Lcorn[5] + (float)rowc) * inv;
    float tw = fabsf(xm_t - xc_t) * 2.0f;
    float th = fabsf(ym_t - yc_t) * 2.0f;

    float score[NBOX];
#pragma unroll
    for (int i = 0; i < NBOX; ++i) {
        float cat = 0.0f;
#pragma unroll
        for (int k = 0; k < NCLS; ++k) {
            float d1 = Pcell[268 + i * NCLS + k] - Lcell[BASE + k];
            float d2 = Pcorn[308 + i * NCLS + k] - Lcorn[BASE + NCLS + k];
            cat += d1 * d1 + d2 * d2;
        }
        float conn_m = Pcell[12 + i * 64 + rowc] * Pcell[12 + i * 64 + 32 + colc];
        float conn_c = Pcorn[140 + i * 64 + r]   * Pcorn[140 + i * 64 + 32 + c];
        float conn = (conn_m + conn_c) * 0.5f;
        // faithful-to-source channel offsets by col/row
        float xm_p = Pcell[(NBOX + i) * 2 + 0 + c] * inv;
        float ym_p = Pcell[(NBOX + i) * 2 + 1 + r] * inv;
        float xc_p = Pcorn[(NBOX * 2 + i) * 2 + 0 + colc] * inv;
        float yc_p = Pcorn[(NBOX * 2 + i) * 2 + 1 + rowc] * inv;
        float ow = fabsf(xm_p - xc_p) * 2.0f;
        float oh = fabsf(ym_p - yc_p) * 2.0f;
        float w = fminf(xm_p + ow * 0.5f, xm_t + tw * 0.5f)
                - fmaxf(xm_p - ow * 0.5f, xm_t - tw * 0.5f);
        float h = fminf(ym_p + oh * 0.5f, ym_t + th * 0.5f)
                - fmaxf(ym_p - oh * 0.5f, ym_t - th * 0.5f);
        float inter = (w < 0.0f || h < 0.0f) ? 0.0f : w * h;
        float uni = ow * oh + tw * th - inter;
        float iou = inter / uni;
        float rmse = (xm_p - xm_t) * (xm_p - xm_t) + (ym_p - ym_t) * (ym_p - ym_t)
                   + (ow - tw) * (ow - tw) + (oh - th) * (oh - th);
        score[i] = conn * (iou - rmse + 0.1f) + 0.1f * (2.0f - cat);
    }
    const int best = (score[1] > score[0]) ? 1 : 0;

    if (lane == 0) {
        atomicOr(g_mask + wave,    1u | ((unsigned)best << 1));
        atomicOr(g_mask + cornIdx, 4u << best);
    }
}

// ---------------------------------------------------------------------------
// Kernel B: emit. One wave per cell writes the FULL output rows (replaces any
// output memset). Channel membership is a branchless range test against the
// 4-bit record. Wave-uniform record -> the ~85% all-zero cells take a
// zero-store fast path. Resets the record to 0 for the next timed iteration.
//
// pred row sets (d = channel):
//   flag : {b0}, {4+2b0, 5+2b0}, [12+64b0, +64), [268+20b0, +20)
//   c0   : {2},  {8,9},          [140, +64),     [308, +20)
//   c1   : {3},  {10,11},        [204, +64),     [328, +20)
// label row sets:
//   flag : {0}, {2,3}, [6,70),  [134,154)
//   c0|c1: {1}, {4,5}, [70,134),[154,174)
// ---------------------------------------------------------------------------
__device__ __forceinline__ bool in_rng(int d, int lo, int n) {
    return (unsigned)(d - lo) < (unsigned)n;
}

__global__ __launch_bounds__(256) void emit_kernel(
    float* __restrict__ out0,   // pred_mask  [B,R,C,CHP]
    float* __restrict__ out1,   // label_mask [B,R,C,CH]
    float* __restrict__ out2)   // label_mask copy
{
    const int cell = (blockIdx.x << 2) | (threadIdx.x >> 6);
    const int lane = threadIdx.x & 63;

    const unsigned m = g_mask[cell];
    if (lane == 0) g_mask[cell] = 0;   // self-clean for the next iteration

    float4* pm4 = (float4*)(out0 + (size_t)cell * CHP);  // 348%4==0 -> 16B-aligned rows
    float2* l1  = (float2*)(out1 + (size_t)cell * CH);   // 174%2==0 -> 8B-aligned rows
    float2* l2  = (float2*)(out2 + (size_t)cell * CH);

    if (m == 0) {   // wave-uniform fast path: all-zero rows
        const float4 z4 = make_float4(0.f, 0.f, 0.f, 0.f);
        const float2 z2 = make_float2(0.f, 0.f);
#pragma unroll
        for (int k = 0; k < 2; ++k) {
            int i = lane + (k << 6);
            if (i < 87) { pm4[i] = z4; l1[i] = z2; l2[i] = z2; }
        }
        return;
    }

    const int flag = m & 1;
    const int b0   = (m >> 1) & 1;
    const int c0   = (m >> 2) & 1;
    const int c1   = (m >> 3) & 1;
    const int cc   = c0 | c1;

    // pred_mask row: 87 float4
#pragma unroll
    for (int k = 0; k < 2; ++k) {
        int i = lane + (k << 6);
        if (i < 87) {
            float v[4];
#pragma unroll
            for (int j = 0; j < 4; ++j) {
                int d = (i << 2) + j;
                bool s = false;
                if (flag) s = (d == b0) | in_rng(d, 4 + 2 * b0, 2)
                            | in_rng(d, 12 + 64 * b0, 64) | in_rng(d, 268 + 20 * b0, 20);
                if (c0)   s |= (d == 2) | in_rng(d, 8, 2)
                            | in_rng(d, 140, 64) | in_rng(d, 308, 20);
                if (c1)   s |= (d == 3) | in_rng(d, 10, 2)
                            | in_rng(d, 204, 64) | in_rng(d, 328, 20);
                v[j] = s ? 1.0f : 0.0f;
            }
            pm4[i] = make_float4(v[0], v[1], v[2], v[3]);
        }
    }

    // label_mask rows (x2): 87 float2
#pragma unroll
    for (int k = 0; k < 2; ++k) {
        int i = lane + (k << 6);
        if (i < 87) {
            float v[2];
#pragma unroll
            for (int j = 0; j < 2; ++j) {
                int d = (i << 1) + j;
                bool s = false;
                if (flag) s = (d == 0) | in_rng(d, 2, 2) | in_rng(d, 6, 64) | in_rng(d, 134, 20);
                if (cc)   s |= (d == 1) | in_rng(d, 4, 2) | in_rng(d, 70, 64) | in_rng(d, 154, 20);
                v[j] = s ? 1.0f : 0.0f;
            }
            float2 p = make_float2(v[0], v[1]);
            l1[i] = p;
            l2[i] = p;
        }
    }
}

extern "C" void kernel_launch(void* const* d_in, const int* in_sizes, int n_in,
                              void* d_out, int out_size, void* d_ws, size_t ws_size,
                              hipStream_t stream) {
    const float* pred  = (const float*)d_in[0];
    const float* label = (const float*)d_in[1];
    // d_in[2]/d_in[3] = num_box/num_class, hard-coded as NBOX/NCLS

    float* out0 = (float*)d_out;                                   // pred_mask
    float* out1 = out0 + (size_t)Bdim * Rdim * Cdim * CHP;         // label_mask
    float* out2 = out1 + (size_t)Bdim * Rdim * Cdim * CH;          // label_mask copy

    // No memsets, no d_ws use: emit_kernel writes every output byte (zeros
    // included) and self-cleans the static mask buffer.
    const int blocks = NCELL / 4;                  // 4 waves per 256-thread block
    match_kernel<<<blocks, 256, 0, stream>>>(pred, label);
    emit_kernel<<<blocks, 256, 0, stream>>>(out0, out1, out2);
}